// Round 1
// baseline (3981.606 us; speedup 1.0000x reference)
//
#include <hip/hip_runtime.h>
#include <hip/hip_bf16.h>
#include <math.h>

#define BB 8
#define LL 2500
#define DD 100
#define FF 50
#define YY 8000
#define VV 50002
#define KS 9
#define PADW 4

#define LT 32
#define NLB 79   // ceil(2500/32)
#define YT 8

// ---- kernel W: transpose conv_w [F][D][K] -> wT [F][K][D] (fp32) ----
__global__ void k_wt(const float* __restrict__ cw, float* __restrict__ wT) {
    int i = blockIdx.x * blockDim.x + threadIdx.x;
    if (i >= FF * DD * KS) return;
    int f = i / (DD * KS);
    int r = i - f * (DD * KS);
    int d = r / KS;
    int k = r - d * KS;
    wT[(f * KS + k) * DD + d] = cw[i];
}

// ---- kernel A: embed-gather + conv1d(same) + bias + tanh -> h[B][L][F] ----
__global__ __launch_bounds__(256) void k_conv(const int* __restrict__ x,
                                              const float* __restrict__ embW,
                                              const float* __restrict__ wT,
                                              const float* __restrict__ cb,
                                              float* __restrict__ h) {
    __shared__ float sE[(LT + KS - 1) * DD];  // 40*100 fp32 = 16 KB
    int b = blockIdx.x / NLB;
    int l0 = (blockIdx.x % NLB) * LT;
    int tid = threadIdx.x;
    for (int i = tid; i < (LT + KS - 1) * DD; i += 256) {
        int row = i / DD;
        int d = i - row * DD;
        int gl = l0 - PADW + row;
        float v = 0.f;
        if (gl >= 0 && gl < LL) {
            int id = x[b * LL + gl];
            v = embW[(size_t)id * DD + d];
        }
        sE[i] = v;
    }
    __syncthreads();

    int f0 = tid & 31;        // 0..31 (all valid, F=50)
    int f1 = f0 + 32;         // 32..63, valid when <50
    bool f1a = (f1 < FF);
    int lb = tid >> 5;        // 0..7 -> l_local = lb*4 + j
    float acc0[4] = {0.f, 0.f, 0.f, 0.f};
    float acc1[4] = {0.f, 0.f, 0.f, 0.f};

    for (int k = 0; k < KS; ++k) {
        const float4* w0 = reinterpret_cast<const float4*>(wT + (f0 * KS + k) * DD);
        const float4* w1 = reinterpret_cast<const float4*>(wT + (f1 * KS + k) * DD);
        for (int d4 = 0; d4 < DD / 4; ++d4) {
            float4 wa = w0[d4];
            float4 wb = f1a ? w1[d4] : make_float4(0.f, 0.f, 0.f, 0.f);
#pragma unroll
            for (int j = 0; j < 4; ++j) {
                const float4 e4 = *reinterpret_cast<const float4*>(
                    &sE[(lb * 4 + j + k) * DD + d4 * 4]);
                acc0[j] += wa.x * e4.x + wa.y * e4.y + wa.z * e4.z + wa.w * e4.w;
                acc1[j] += wb.x * e4.x + wb.y * e4.y + wb.z * e4.z + wb.w * e4.w;
            }
        }
    }
    float b0 = cb[f0];
    float b1 = f1a ? cb[f1] : 0.f;
    for (int j = 0; j < 4; ++j) {
        int l = l0 + lb * 4 + j;
        if (l < LL) {
            size_t base = (size_t)(b * LL + l) * FF;
            h[base + f0] = tanhf(acc0[j] + b0);
            if (f1a) h[base + f1] = tanhf(acc1[j] + b1);
        }
    }
}

// ---- kernel B: fused scores -> softmax -> alpha out -> m -> yhat -> BCE ----
__global__ __launch_bounds__(256) void k_attn(const float* __restrict__ h,
                                              const float* __restrict__ Uw,
                                              const float* __restrict__ fw,
                                              const float* __restrict__ fb,
                                              const float* __restrict__ tgt,
                                              float* __restrict__ out,
                                              float* __restrict__ lossAcc) {
    __shared__ float sS[YT * LL];   // 80000 B
    __shared__ float sU[YT * FF];   // 1600 B
    __shared__ float sRed[32];

    int b = blockIdx.x / (YY / YT);
    int y0 = (blockIdx.x % (YY / YT)) * YT;
    int tid = threadIdx.x;

    for (int i = tid; i < YT * FF; i += 256) {
        int yy = i / FF;
        int f = i - yy * FF;
        sU[i] = Uw[(size_t)(y0 + yy) * FF + f];
    }
    __syncthreads();

    int yy = tid >> 5;   // group (one label each)
    int li = tid & 31;   // lane in group

    // U row for this label into registers
    float u[FF];
#pragma unroll
    for (int f = 0; f < FF; ++f) u[f] = sU[yy * FF + f];

    // phase 1: scores + running max
    float mx = -1e30f;
    for (int l = li; l < LL; l += 32) {
        const float2* hr = reinterpret_cast<const float2*>(h + (size_t)(b * LL + l) * FF);
        float s = 0.f;
#pragma unroll
        for (int i = 0; i < FF / 2; ++i) {
            float2 hv = hr[i];
            s += hv.x * u[2 * i] + hv.y * u[2 * i + 1];
        }
        sS[yy * LL + l] = s;
        mx = fmaxf(mx, s);
    }
#pragma unroll
    for (int o = 16; o > 0; o >>= 1) mx = fmaxf(mx, __shfl_xor(mx, o, 32));
    if (li == 0) sRed[yy] = mx;
    __syncthreads();

    // phase 2: exp + sum, then alpha (to global + back to LDS)
    mx = sRed[yy];
    float sum = 0.f;
    for (int l = li; l < LL; l += 32) {
        float e = __expf(sS[yy * LL + l] - mx);
        sS[yy * LL + l] = e;
        sum += e;
    }
#pragma unroll
    for (int o = 16; o > 0; o >>= 1) sum += __shfl_xor(sum, o, 32);
    if (li == 0) sRed[8 + yy] = sum;
    __syncthreads();

    float inv = 1.f / sRed[8 + yy];
    float* alphaOut = out + 64001 + (size_t)(b * YY + y0) * LL;
    for (int l = li; l < LL; l += 32) {
        float a = sS[yy * LL + l] * inv;
        sS[yy * LL + l] = a;
        alphaOut[(size_t)yy * LL + l] = a;
    }
    __syncthreads();

    // phase 3: m[yy][f] = sum_l alpha * h   (thread owns (yy, f0[, f1]))
    int f0 = li;
    int f1 = f0 + 32;
    bool f1a = (f1 < FF);
    const float* hb = h + (size_t)b * LL * FF;
    const float* aRow = &sS[yy * LL];
    float m0a = 0.f, m0b = 0.f, m0c = 0.f, m0d = 0.f;
    float m1a = 0.f, m1b = 0.f, m1c = 0.f, m1d = 0.f;
    for (int l = 0; l < LL; l += 4) {   // 2500 % 4 == 0
        float a0 = aRow[l], a1 = aRow[l + 1], a2 = aRow[l + 2], a3 = aRow[l + 3];
        const float* h0 = hb + (size_t)l * FF;
        m0a += a0 * h0[f0];
        m0b += a1 * h0[FF + f0];
        m0c += a2 * h0[2 * FF + f0];
        m0d += a3 * h0[3 * FF + f0];
        if (f1a) {
            m1a += a0 * h0[f1];
            m1b += a1 * h0[FF + f1];
            m1c += a2 * h0[2 * FF + f1];
            m1d += a3 * h0[3 * FF + f1];
        }
    }
    float m0 = (m0a + m0b) + (m0c + m0d);
    float m1 = (m1a + m1b) + (m1c + m1d);

    // phase 4: yhat + BCE
    int y = y0 + yy;
    float p = m0 * fw[(size_t)y * FF + f0];
    if (f1a) p += m1 * fw[(size_t)y * FF + f1];
#pragma unroll
    for (int o = 16; o > 0; o >>= 1) p += __shfl_xor(p, o, 32);
    if (li == 0) {
        float z = p + fb[y];
        out[(size_t)b * YY + y] = z;
        float t = tgt[(size_t)b * YY + y];
        float bce = fmaxf(z, 0.f) - z * t + log1pf(expf(-fabsf(z)));
        atomicAdd(lossAcc, bce);
    }
}

// ---- kernel C: finalize loss ----
__global__ void k_loss(const float* __restrict__ acc, float* __restrict__ out) {
    out[64000] = acc[0] / (float)(BB * YY);
}

extern "C" void kernel_launch(void* const* d_in, const int* in_sizes, int n_in,
                              void* d_out, int out_size, void* d_ws, size_t ws_size,
                              hipStream_t stream) {
    const int*   x    = (const int*)d_in[0];
    const float* tgt  = (const float*)d_in[1];
    const float* embW = (const float*)d_in[2];
    const float* cw   = (const float*)d_in[3];
    const float* cb   = (const float*)d_in[4];
    const float* Uw   = (const float*)d_in[5];
    const float* fw   = (const float*)d_in[6];
    const float* fb   = (const float*)d_in[7];
    float* out = (float*)d_out;

    float* lossAcc = (float*)d_ws;
    float* wT = (float*)((char*)d_ws + 256);                  // 45000 f32
    float* h  = (float*)((char*)d_ws + 256 + 184064);         // B*L*F f32 = 4 MB

    hipMemsetAsync(d_ws, 0, 4, stream);
    k_wt<<<(FF * DD * KS + 255) / 256, 256, 0, stream>>>(cw, wT);
    k_conv<<<BB * NLB, 256, 0, stream>>>(x, embW, wT, cb, h);
    k_attn<<<BB * (YY / YT), 256, 0, stream>>>(h, Uw, fw, fb, tgt, out, lossAcc);
    k_loss<<<1, 1, 0, stream>>>(lossAcc, out);
}

// Round 2
// 826.574 us; speedup vs baseline: 4.8170x; 4.8170x over previous
//
#include <hip/hip_runtime.h>
#include <hip/hip_bf16.h>
#include <math.h>

#define BB 8
#define LL 2500
#define LPAD 2560
#define DD 100
#define FF 50
#define FP 64
#define YY 8000
#define KS 9
#define PADW 4

#define LT 32
#define NLB2 80   // 2560/32 l-tiles for conv (covers zero pad)
#define YB 64

typedef __attribute__((ext_vector_type(8))) short short8;
typedef __attribute__((ext_vector_type(4))) float f32x4;
typedef float f32x4u __attribute__((ext_vector_type(4), aligned(4)));

__device__ inline f32x4 mfma_bf16(short8 a, short8 b, f32x4 c) {
    return __builtin_amdgcn_mfma_f32_16x16x32_bf16(a, b, c, 0, 0, 0);
}

__device__ inline unsigned short f2bf(float x) {
    unsigned int u = __builtin_bit_cast(unsigned int, x);
    unsigned int r = u + 0x7fffu + ((u >> 16) & 1u);
    return (unsigned short)(r >> 16);
}

__device__ inline unsigned long long pack4bf(const float* a) {
    return (unsigned long long)f2bf(a[0])
         | ((unsigned long long)f2bf(a[1]) << 16)
         | ((unsigned long long)f2bf(a[2]) << 32)
         | ((unsigned long long)f2bf(a[3]) << 48);
}

// ---- kernel W: transpose conv_w [F][D][K] -> wT [F][K][D] ----
__global__ void k_wt(const float* __restrict__ cw, float* __restrict__ wT) {
    int i = blockIdx.x * blockDim.x + threadIdx.x;
    if (i >= FF * DD * KS) return;
    int f = i / (DD * KS);
    int r = i - f * (DD * KS);
    int d = r / KS;
    int k = r - d * KS;
    wT[(f * KS + k) * DD + d] = cw[i];
}

// ---- kernel U: U_w fp32 [Y][50] -> bf16 [Y][64] (f-pad zeros) ----
__global__ void k_ubf(const float* __restrict__ Uw, unsigned short* __restrict__ Ub) {
    int i = blockIdx.x * blockDim.x + threadIdx.x;
    if (i >= YY * FP) return;
    int y = i >> 6, f = i & 63;
    float v = (f < FF) ? Uw[y * FF + f] : 0.f;
    Ub[i] = f2bf(v);
}

// ---- kernel A: embed + conv1d + tanh -> hB[b][2560][64] bf16, hT[b][64][2560] bf16 ----
__global__ __launch_bounds__(256) void k_conv(const int* __restrict__ x,
                                              const float* __restrict__ embW,
                                              const float* __restrict__ wT,
                                              const float* __restrict__ cb,
                                              unsigned short* __restrict__ hB,
                                              unsigned short* __restrict__ hT) {
    __shared__ float sE[(LT + KS - 1) * DD];
    int b = blockIdx.x / NLB2;
    int l0 = (blockIdx.x % NLB2) * LT;
    int tid = threadIdx.x;
    for (int i = tid; i < (LT + KS - 1) * DD; i += 256) {
        int row = i / DD;
        int d = i - row * DD;
        int gl = l0 - PADW + row;
        float v = 0.f;
        if (gl >= 0 && gl < LL) {
            int id = x[b * LL + gl];
            v = embW[(size_t)id * DD + d];
        }
        sE[i] = v;
    }
    __syncthreads();

    int f0 = tid & 31;
    int f1 = f0 + 32;
    bool f1a = (f1 < FF);
    int lb = tid >> 5;
    float acc0[4] = {0.f, 0.f, 0.f, 0.f};
    float acc1[4] = {0.f, 0.f, 0.f, 0.f};

    for (int k = 0; k < KS; ++k) {
        const float4* w0 = reinterpret_cast<const float4*>(wT + (f0 * KS + k) * DD);
        const float4* w1 = reinterpret_cast<const float4*>(wT + (f1 * KS + k) * DD);
        for (int d4 = 0; d4 < DD / 4; ++d4) {
            float4 wa = w0[d4];
            float4 wb = f1a ? w1[d4] : make_float4(0.f, 0.f, 0.f, 0.f);
#pragma unroll
            for (int j = 0; j < 4; ++j) {
                const float4 e4 = *reinterpret_cast<const float4*>(
                    &sE[(lb * 4 + j + k) * DD + d4 * 4]);
                acc0[j] += wa.x * e4.x + wa.y * e4.y + wa.z * e4.z + wa.w * e4.w;
                acc1[j] += wb.x * e4.x + wb.y * e4.y + wb.z * e4.z + wb.w * e4.w;
            }
        }
    }
    float b0 = cb[f0];
    float b1 = f1a ? cb[f1] : 0.f;
    float t0[4], t1[4];
#pragma unroll
    for (int j = 0; j < 4; ++j) {
        int l = l0 + lb * 4 + j;
        bool lv = (l < LL);
        t0[j] = lv ? tanhf(acc0[j] + b0) : 0.f;
        t1[j] = (lv && f1a) ? tanhf(acc1[j] + b1) : 0.f;
        size_t base = ((size_t)b * LPAD + l) * FP;
        hB[base + f0] = f2bf(t0[j]);
        hB[base + f1] = f2bf(t1[j]);
    }
    *(unsigned long long*)&hT[((size_t)b * FP + f0) * LPAD + l0 + lb * 4] = pack4bf(t0);
    *(unsigned long long*)&hT[((size_t)b * FP + f1) * LPAD + l0 + lb * 4] = pack4bf(t1);
}

// ---- kernel B: fused scores(MFMA) -> softmax -> alpha -> m(MFMA) -> yhat -> BCE ----
__global__ __launch_bounds__(256) void k_attn2(const unsigned short* __restrict__ hB,
                                               const unsigned short* __restrict__ hT,
                                               const unsigned short* __restrict__ Ub,
                                               const float* __restrict__ fw,
                                               const float* __restrict__ fb,
                                               const float* __restrict__ tgt,
                                               float* __restrict__ out,
                                               float* __restrict__ lossAcc) {
    __shared__ char sH[8192];    // h tile  [64 l][64 f] bf16, XOR-swizzled
    __shared__ char sHT[8192];   // hT tile [64 f][64 l] bf16, XOR-swizzled
    __shared__ char sA[8192];    // alpha   [64 y][64 l] bf16, XOR-swizzled
    __shared__ float sRed[4 * 64];
    __shared__ float sInv[64];

    int b = blockIdx.x & 7;                 // b == XCD id (round-robin) -> L2 locality
    int y0 = (blockIdx.x >> 3) * YB;
    int tid = threadIdx.x;
    int w = tid >> 6;
    int lane = tid & 63;
    int lm = lane & 15, g = lane >> 4;

    const unsigned short* hBb = hB + (size_t)b * LPAD * FP;
    const unsigned short* hTb = hT + (size_t)b * FP * LPAD;

    // U fragments (B operand of scores MFMA), kept in registers
    short8 uf[4][2];
#pragma unroll
    for (int yt = 0; yt < 4; ++yt)
#pragma unroll
        for (int kh = 0; kh < 2; ++kh)
            uf[yt][kh] = *(const short8*)(Ub + (size_t)(y0 + yt * 16 + lm) * FP + g * 8 + kh * 32);

    int r = w * 16 + lm;
    int rx = (r & 7) << 4;

    // ---------------- pass 1: softmax denominators ----------------
    float ssum[4] = {0.f, 0.f, 0.f, 0.f};
    for (int lt = 0; lt < 40; ++lt) {
        const float4* src = (const float4*)(hBb + (size_t)(lt * 64) * FP);
#pragma unroll
        for (int it = 0; it < 2; ++it) {
            int i = tid + it * 256;
            int row = i >> 3, c = i & 7;
            *(float4*)&sH[row * 128 + ((c * 16) ^ ((row & 7) << 4))] = src[row * 8 + c];
        }
        __syncthreads();
        short8 a0 = *(const short8*)&sH[r * 128 + ((g * 16) ^ rx)];
        short8 a1 = *(const short8*)&sH[r * 128 + ((g * 16 + 64) ^ rx)];
        int lbase = lt * 64 + w * 16 + g * 4;
#pragma unroll
        for (int yt = 0; yt < 4; ++yt) {
            f32x4 c = {0.f, 0.f, 0.f, 0.f};
            c = mfma_bf16(a0, uf[yt][0], c);
            c = mfma_bf16(a1, uf[yt][1], c);
            float p = 0.f;
#pragma unroll
            for (int j = 0; j < 4; ++j)
                p += (lbase + j < LL) ? __expf(c[j]) : 0.f;
            ssum[yt] += p;
        }
        __syncthreads();
    }
#pragma unroll
    for (int yt = 0; yt < 4; ++yt) {
        float s = ssum[yt];
        s += __shfl_xor(s, 16);
        s += __shfl_xor(s, 32);
        if (g == 0) sRed[w * 64 + yt * 16 + lm] = s;
    }
    __syncthreads();
    if (tid < 64) {
        float s = sRed[tid] + sRed[64 + tid] + sRed[128 + tid] + sRed[192 + tid];
        sInv[tid] = 1.f / s;
    }
    __syncthreads();

    // ---------------- pass 2: alpha out + m accumulation ----------------
    f32x4 macc[4];
#pragma unroll
    for (int ft = 0; ft < 4; ++ft) macc[ft] = (f32x4){0.f, 0.f, 0.f, 0.f};

    float* alphaBase = out + 64001;
    for (int lt = 0; lt < 40; ++lt) {
        const float4* src = (const float4*)(hBb + (size_t)(lt * 64) * FP);
#pragma unroll
        for (int it = 0; it < 2; ++it) {
            int i = tid + it * 256;
            int row = i >> 3, c = i & 7;
            *(float4*)&sH[row * 128 + ((c * 16) ^ ((row & 7) << 4))] = src[row * 8 + c];
            float4 vT = *(const float4*)(hTb + (size_t)row * LPAD + lt * 64 + c * 8);
            *(float4*)&sHT[row * 128 + ((c * 16) ^ ((row & 7) << 4))] = vT;
        }
        __syncthreads();
        short8 a0 = *(const short8*)&sH[r * 128 + ((g * 16) ^ rx)];
        short8 a1 = *(const short8*)&sH[r * 128 + ((g * 16 + 64) ^ rx)];
        int lbase = lt * 64 + w * 16 + g * 4;
#pragma unroll
        for (int yt = 0; yt < 4; ++yt) {
            f32x4 c = {0.f, 0.f, 0.f, 0.f};
            c = mfma_bf16(a0, uf[yt][0], c);
            c = mfma_bf16(a1, uf[yt][1], c);
            float inv = sInv[yt * 16 + lm];
            float a[4];
#pragma unroll
            for (int j = 0; j < 4; ++j)
                a[j] = (lbase + j < LL) ? __expf(c[j]) * inv : 0.f;
            if (lbase < LL) {
                int y = y0 + yt * 16 + lm;
                *(f32x4u*)(alphaBase + (size_t)(b * YY + y) * LL + lbase) =
                    (f32x4u){a[0], a[1], a[2], a[3]};
            }
            int yl = yt * 16 + lm;
            *(unsigned long long*)&sA[yl * 128 + ((w * 32 + g * 8) ^ ((yl & 7) << 4))] =
                pack4bf(a);
        }
        __syncthreads();
        // m MFMA: wave w owns y-rows w*16..w*16+15
        int yr = w * 16 + lm;
        int yx = (yr & 7) << 4;
        short8 pa0 = *(const short8*)&sA[yr * 128 + ((g * 16) ^ yx)];
        short8 pa1 = *(const short8*)&sA[yr * 128 + ((g * 16 + 64) ^ yx)];
#pragma unroll
        for (int ft = 0; ft < 4; ++ft) {
            int fr = ft * 16 + lm;
            int fx = (fr & 7) << 4;
            short8 b0 = *(const short8*)&sHT[fr * 128 + ((g * 16) ^ fx)];
            short8 b1 = *(const short8*)&sHT[fr * 128 + ((g * 16 + 64) ^ fx)];
            macc[ft] = mfma_bf16(pa0, b0, macc[ft]);
            macc[ft] = mfma_bf16(pa1, b1, macc[ft]);
        }
        __syncthreads();
    }

    // ---------------- epilogue: yhat + BCE ----------------
    float bsum = 0.f;
#pragma unroll
    for (int j = 0; j < 4; ++j) {
        int y = y0 + w * 16 + g * 4 + j;
        float z = 0.f;
#pragma unroll
        for (int ft = 0; ft < 4; ++ft) {
            int f = ft * 16 + lm;
            float fwv = (f < FF) ? fw[(size_t)y * FF + f] : 0.f;
            z += macc[ft][j] * fwv;
        }
        z += __shfl_xor(z, 1);
        z += __shfl_xor(z, 2);
        z += __shfl_xor(z, 4);
        z += __shfl_xor(z, 8);
        if (lm == 0) {
            z += fb[y];
            out[b * YY + y] = z;
            float t = tgt[b * YY + y];
            bsum += fmaxf(z, 0.f) - z * t + log1pf(__expf(-fabsf(z)));
        }
    }
    bsum += __shfl_xor(bsum, 16);
    bsum += __shfl_xor(bsum, 32);
    if (lane == 0) atomicAdd(lossAcc, bsum);
}

// ---- kernel C: finalize loss ----
__global__ void k_loss(const float* __restrict__ acc, float* __restrict__ out) {
    out[64000] = acc[0] / (float)(BB * YY);
}

extern "C" void kernel_launch(void* const* d_in, const int* in_sizes, int n_in,
                              void* d_out, int out_size, void* d_ws, size_t ws_size,
                              hipStream_t stream) {
    const int*   x    = (const int*)d_in[0];
    const float* tgt  = (const float*)d_in[1];
    const float* embW = (const float*)d_in[2];
    const float* cw   = (const float*)d_in[3];
    const float* cb   = (const float*)d_in[4];
    const float* Uw   = (const float*)d_in[5];
    const float* fw   = (const float*)d_in[6];
    const float* fb   = (const float*)d_in[7];
    float* out = (float*)d_out;

    float*          lossAcc = (float*)d_ws;
    float*          wT = (float*)((char*)d_ws + 256);             // 45000 f32
    unsigned short* Ub = (unsigned short*)((char*)d_ws + 184320); // 8000*64 bf16 = 1.0 MB
    unsigned short* hB = (unsigned short*)((char*)d_ws + 1212416);// 8*2560*64 bf16 = 2.6 MB
    unsigned short* hT = (unsigned short*)((char*)d_ws + 3837952);// 8*64*2560 bf16 = 2.6 MB

    hipMemsetAsync(d_ws, 0, 4, stream);
    k_wt  <<<(FF * DD * KS + 255) / 256, 256, 0, stream>>>(cw, wT);
    k_ubf <<<(YY * FP + 255) / 256, 256, 0, stream>>>(Uw, Ub);
    k_conv<<<BB * NLB2, 256, 0, stream>>>(x, embW, wT, cb, hB, hT);
    k_attn2<<<125 * 8, 256, 0, stream>>>(hB, hT, Ub, fw, fb, tgt, out, lossAcc);
    k_loss<<<1, 1, 0, stream>>>(lossAcc, out);
}

// Round 3
// 561.509 us; speedup vs baseline: 7.0909x; 1.4721x over previous
//
#include <hip/hip_runtime.h>
#include <hip/hip_bf16.h>
#include <math.h>

#define BB 8
#define LL 2500
#define LPAD 2560
#define DD 100
#define FF 50
#define FP 64
#define YY 8000
#define KS 9
#define PADW 4

#define LT 32
#define NLB2 80
#define YB 64

typedef __attribute__((ext_vector_type(8))) short short8;
typedef __attribute__((ext_vector_type(4))) float f32x4;
typedef float f32x4u __attribute__((ext_vector_type(4), aligned(4)));

__device__ inline f32x4 mfma_bf16(short8 a, short8 b, f32x4 c) {
    return __builtin_amdgcn_mfma_f32_16x16x32_bf16(a, b, c, 0, 0, 0);
}

__device__ inline unsigned short f2bf(float x) {
    unsigned int u = __builtin_bit_cast(unsigned int, x);
    unsigned int r = u + 0x7fffu + ((u >> 16) & 1u);
    return (unsigned short)(r >> 16);
}

__device__ inline unsigned long long pack4bf(const float* a) {
    return (unsigned long long)f2bf(a[0])
         | ((unsigned long long)f2bf(a[1]) << 16)
         | ((unsigned long long)f2bf(a[2]) << 32)
         | ((unsigned long long)f2bf(a[3]) << 48);
}

// ---- prep: conv_w [F][D][K] -> wT [F][K][D]; U_w fp32 -> bf16 [Y][64] ----
__global__ void k_prep(const float* __restrict__ cw, float* __restrict__ wT,
                       const float* __restrict__ Uw, unsigned short* __restrict__ Ub) {
    int i = blockIdx.x * blockDim.x + threadIdx.x;
    if (i < FF * DD * KS) {
        int f = i / (DD * KS);
        int r = i - f * (DD * KS);
        int d = r / KS;
        int k = r - d * KS;
        wT[(f * KS + k) * DD + d] = cw[i];
    }
    if (i < YY * FP) {
        int y = i >> 6, f = i & 63;
        float v = (f < FF) ? Uw[y * FF + f] : 0.f;
        Ub[i] = f2bf(v);
    }
}

// ---- kernel A: embed + conv1d + tanh -> hB[b][2560][64] bf16, hT[b][64][2560] bf16 ----
__global__ __launch_bounds__(256, 4) void k_conv(const int* __restrict__ x,
                                                 const float* __restrict__ embW,
                                                 const float* __restrict__ wT,
                                                 const float* __restrict__ cb,
                                                 unsigned short* __restrict__ hB,
                                                 unsigned short* __restrict__ hT) {
    __shared__ float sE[(LT + 8) * DD];   // 40*100 = 16 KB
    __shared__ int sX[LT + 8];
    int b = blockIdx.x / NLB2;
    int l0 = (blockIdx.x % NLB2) * LT;
    int tid = threadIdx.x;

    if (tid < LT + 8) {
        int gl = l0 - PADW + tid;
        sX[tid] = (gl >= 0 && gl < LL) ? x[b * LL + gl] : -1;
    }
    __syncthreads();
    // gather: 1000 float4 items (40 rows x 25 d4)
    for (int i = tid; i < (LT + 8) * (DD / 4); i += 256) {
        int row = i / (DD / 4);
        int d4 = i - row * (DD / 4);
        int id = sX[row];
        float4 v = make_float4(0.f, 0.f, 0.f, 0.f);
        if (id >= 0) v = *(const float4*)(embW + (size_t)id * DD + d4 * 4);
        *(float4*)&sE[row * DD + d4 * 4] = v;
    }
    __syncthreads();

    int f0 = tid & 31;
    int f1 = f0 + 32;
    bool f1a = (f1 < FF);
    int lb = tid >> 5;
    const float* eRow = &sE[lb * 4 * DD];
    const float* w0p = wT + (size_t)f0 * (KS * DD);
    const float* w1p = wT + (size_t)(f1a ? f1 : f0) * (KS * DD);
    float acc0[4] = {0.f, 0.f, 0.f, 0.f};
    float acc1[4] = {0.f, 0.f, 0.f, 0.f};

    for (int d4 = 0; d4 < DD / 4; ++d4) {
        float4 e[12];
#pragma unroll
        for (int r = 0; r < 12; ++r)
            e[r] = *(const float4*)(eRow + r * DD + d4 * 4);
#pragma unroll
        for (int k = 0; k < KS; ++k) {
            float4 wa = *(const float4*)(w0p + k * DD + d4 * 4);
            float4 wb = *(const float4*)(w1p + k * DD + d4 * 4);
#pragma unroll
            for (int j = 0; j < 4; ++j) {
                float4 ev = e[k + j];
                acc0[j] += wa.x * ev.x + wa.y * ev.y + wa.z * ev.z + wa.w * ev.w;
                acc1[j] += wb.x * ev.x + wb.y * ev.y + wb.z * ev.z + wb.w * ev.w;
            }
        }
    }
    float b0 = cb[f0];
    float b1 = f1a ? cb[f1] : 0.f;
    if (!f1a) { acc1[0] = acc1[1] = acc1[2] = acc1[3] = 0.f; b1 = 0.f; }
    float t0[4], t1[4];
#pragma unroll
    for (int j = 0; j < 4; ++j) {
        int l = l0 + lb * 4 + j;
        bool lv = (l < LL);
        t0[j] = lv ? tanhf(acc0[j] + b0) : 0.f;
        t1[j] = (lv && f1a) ? tanhf(acc1[j] + b1) : 0.f;
        size_t base = ((size_t)b * LPAD + l) * FP;
        hB[base + f0] = f2bf(t0[j]);
        hB[base + f1] = f2bf(t1[j]);
    }
    *(unsigned long long*)&hT[((size_t)b * FP + f0) * LPAD + l0 + lb * 4] = pack4bf(t0);
    *(unsigned long long*)&hT[((size_t)b * FP + f1) * LPAD + l0 + lb * 4] = pack4bf(t1);
}

// ---- kernel B: fused scores(MFMA) -> softmax -> alpha -> m(MFMA) -> yhat -> BCE ----
__global__ __launch_bounds__(256) void k_attn2(const unsigned short* __restrict__ hB,
                                               const unsigned short* __restrict__ hT,
                                               const unsigned short* __restrict__ Ub,
                                               const float* __restrict__ fw,
                                               const float* __restrict__ fb,
                                               const float* __restrict__ tgt,
                                               float* __restrict__ out,
                                               float* __restrict__ lossAcc) {
    __shared__ char sH[8192];      // h tile  [64 l][64 f] bf16, XOR-swizzled
    __shared__ char sHT[8192];     // hT tile [64 f][64 l] bf16, XOR-swizzled
    __shared__ char sA[8192];      // alpha   [64 y][64 l] bf16, XOR-swizzled
    __shared__ float sAF[64 * 68]; // alpha fp32 [64 y][64 l], stride 68
    __shared__ float sRed[4 * 64];
    __shared__ float sInv[64];

    int b = blockIdx.x & 7;
    int y0 = (blockIdx.x >> 3) * YB;
    int tid = threadIdx.x;
    int w = tid >> 6;
    int lane = tid & 63;
    int lm = lane & 15, g = lane >> 4;

    const unsigned short* hBb = hB + (size_t)b * LPAD * FP;
    const unsigned short* hTb = hT + (size_t)b * FP * LPAD;

    short8 uf[4][2];
#pragma unroll
    for (int yt = 0; yt < 4; ++yt)
#pragma unroll
        for (int kh = 0; kh < 2; ++kh)
            uf[yt][kh] = *(const short8*)(Ub + (size_t)(y0 + yt * 16 + lm) * FP + g * 8 + kh * 32);

    int r = w * 16 + lm;
    int rx = (r & 7) << 4;

    // ---------------- pass 1: softmax denominators ----------------
    float ssum[4] = {0.f, 0.f, 0.f, 0.f};
    for (int lt = 0; lt < 40; ++lt) {
        const float4* src = (const float4*)(hBb + (size_t)(lt * 64) * FP);
#pragma unroll
        for (int it = 0; it < 2; ++it) {
            int i = tid + it * 256;
            int row = i >> 3, c = i & 7;
            *(float4*)&sH[row * 128 + ((c * 16) ^ ((row & 7) << 4))] = src[row * 8 + c];
        }
        __syncthreads();
        short8 a0 = *(const short8*)&sH[r * 128 + ((g * 16) ^ rx)];
        short8 a1 = *(const short8*)&sH[r * 128 + ((g * 16 + 64) ^ rx)];
        int lbase = lt * 64 + w * 16 + g * 4;
#pragma unroll
        for (int yt = 0; yt < 4; ++yt) {
            f32x4 c = {0.f, 0.f, 0.f, 0.f};
            c = mfma_bf16(a0, uf[yt][0], c);
            c = mfma_bf16(a1, uf[yt][1], c);
            float p = 0.f;
#pragma unroll
            for (int j = 0; j < 4; ++j)
                p += (lbase + j < LL) ? __expf(c[j]) : 0.f;
            ssum[yt] += p;
        }
        __syncthreads();
    }
#pragma unroll
    for (int yt = 0; yt < 4; ++yt) {
        float s = ssum[yt];
        s += __shfl_xor(s, 16);
        s += __shfl_xor(s, 32);
        if (g == 0) sRed[w * 64 + yt * 16 + lm] = s;
    }
    __syncthreads();
    if (tid < 64) {
        float s = sRed[tid] + sRed[64 + tid] + sRed[128 + tid] + sRed[192 + tid];
        sInv[tid] = 1.f / s;
    }
    __syncthreads();

    // ---------------- pass 2: alpha out + m accumulation ----------------
    f32x4 macc[4];
#pragma unroll
    for (int ft = 0; ft < 4; ++ft) macc[ft] = (f32x4){0.f, 0.f, 0.f, 0.f};

    float* alphaBase = out + 64001;
    for (int lt = 0; lt < 40; ++lt) {
        const float4* src = (const float4*)(hBb + (size_t)(lt * 64) * FP);
#pragma unroll
        for (int it = 0; it < 2; ++it) {
            int i = tid + it * 256;
            int row = i >> 3, c = i & 7;
            *(float4*)&sH[row * 128 + ((c * 16) ^ ((row & 7) << 4))] = src[row * 8 + c];
            float4 vT = *(const float4*)(hTb + (size_t)row * LPAD + lt * 64 + c * 8);
            *(float4*)&sHT[row * 128 + ((c * 16) ^ ((row & 7) << 4))] = vT;
        }
        __syncthreads();
        short8 a0 = *(const short8*)&sH[r * 128 + ((g * 16) ^ rx)];
        short8 a1 = *(const short8*)&sH[r * 128 + ((g * 16 + 64) ^ rx)];
        int lbase = lt * 64 + w * 16 + g * 4;
#pragma unroll
        for (int yt = 0; yt < 4; ++yt) {
            f32x4 c = {0.f, 0.f, 0.f, 0.f};
            c = mfma_bf16(a0, uf[yt][0], c);
            c = mfma_bf16(a1, uf[yt][1], c);
            float inv = sInv[yt * 16 + lm];
            float a[4];
#pragma unroll
            for (int j = 0; j < 4; ++j)
                a[j] = (lbase + j < LL) ? __expf(c[j]) * inv : 0.f;
            int yl = yt * 16 + lm;
            *(f32x4*)&sAF[yl * 68 + w * 16 + g * 4] = (f32x4){a[0], a[1], a[2], a[3]};
            *(unsigned long long*)&sA[yl * 128 + ((w * 32 + g * 8) ^ ((yl & 7) << 4))] =
                pack4bf(a);
        }
        __syncthreads();
        // m MFMA
        int yr = w * 16 + lm;
        int yx = (yr & 7) << 4;
        short8 pa0 = *(const short8*)&sA[yr * 128 + ((g * 16) ^ yx)];
        short8 pa1 = *(const short8*)&sA[yr * 128 + ((g * 16 + 64) ^ yx)];
#pragma unroll
        for (int ft = 0; ft < 4; ++ft) {
            int fr = ft * 16 + lm;
            int fx = (fr & 7) << 4;
            short8 b0 = *(const short8*)&sHT[fr * 128 + ((g * 16) ^ fx)];
            short8 b1 = *(const short8*)&sHT[fr * 128 + ((g * 16 + 64) ^ fx)];
            macc[ft] = mfma_bf16(pa0, b0, macc[ft]);
            macc[ft] = mfma_bf16(pa1, b1, macc[ft]);
        }
        // coalesced alpha dump: 256 B contiguous per y-row
        int l0t = lt * 64;
#pragma unroll
        for (int it = 0; it < 4; ++it) {
            int i = tid + it * 256;
            int row = i >> 4;
            int c4 = (i & 15) * 4;
            int l = l0t + c4;
            if (l < LL) {
                f32x4 v = *(f32x4*)&sAF[row * 68 + c4];
                __builtin_nontemporal_store(v,
                    (f32x4u*)(alphaBase + (size_t)(b * YY + y0 + row) * LL + l));
            }
        }
        __syncthreads();
    }

    // ---------------- epilogue: yhat + BCE ----------------
    float bsum = 0.f;
#pragma unroll
    for (int j = 0; j < 4; ++j) {
        int y = y0 + w * 16 + g * 4 + j;
        float z = 0.f;
#pragma unroll
        for (int ft = 0; ft < 4; ++ft) {
            int f = ft * 16 + lm;
            float fwv = (f < FF) ? fw[(size_t)y * FF + f] : 0.f;
            z += macc[ft][j] * fwv;
        }
        z += __shfl_xor(z, 1);
        z += __shfl_xor(z, 2);
        z += __shfl_xor(z, 4);
        z += __shfl_xor(z, 8);
        if (lm == 0) {
            z += fb[y];
            out[b * YY + y] = z;
            float t = tgt[b * YY + y];
            bsum += fmaxf(z, 0.f) - z * t + log1pf(__expf(-fabsf(z)));
        }
    }
    bsum += __shfl_xor(bsum, 16);
    bsum += __shfl_xor(bsum, 32);
    if (lane == 0) atomicAdd(lossAcc, bsum);
}

// ---- kernel C: finalize loss ----
__global__ void k_loss(const float* __restrict__ acc, float* __restrict__ out) {
    out[64000] = acc[0] / (float)(BB * YY);
}

extern "C" void kernel_launch(void* const* d_in, const int* in_sizes, int n_in,
                              void* d_out, int out_size, void* d_ws, size_t ws_size,
                              hipStream_t stream) {
    const int*   x    = (const int*)d_in[0];
    const float* tgt  = (const float*)d_in[1];
    const float* embW = (const float*)d_in[2];
    const float* cw   = (const float*)d_in[3];
    const float* cb   = (const float*)d_in[4];
    const float* Uw   = (const float*)d_in[5];
    const float* fw   = (const float*)d_in[6];
    const float* fb   = (const float*)d_in[7];
    float* out = (float*)d_out;

    float*          lossAcc = (float*)d_ws;
    float*          wT = (float*)((char*)d_ws + 256);             // 45000 f32
    unsigned short* Ub = (unsigned short*)((char*)d_ws + 184320); // 8000*64 bf16
    unsigned short* hB = (unsigned short*)((char*)d_ws + 1212416);// 8*2560*64 bf16
    unsigned short* hT = (unsigned short*)((char*)d_ws + 3837952);// 8*64*2560 bf16

    hipMemsetAsync(d_ws, 0, 4, stream);
    k_prep<<<(YY * FP + 255) / 256, 256, 0, stream>>>(cw, wT, Uw, Ub);
    k_conv<<<BB * NLB2, 256, 0, stream>>>(x, embW, wT, cb, hB, hT);
    k_attn2<<<125 * 8, 256, 0, stream>>>(hB, hT, Ub, fw, fb, tgt, out, lossAcc);
    k_loss<<<1, 1, 0, stream>>>(lossAcc, out);
}

// Round 4
// 490.478 us; speedup vs baseline: 8.1178x; 1.1448x over previous
//
#include <hip/hip_runtime.h>
#include <hip/hip_bf16.h>
#include <math.h>

#define BB 8
#define LL 2500
#define LPAD 2560
#define NT 40          // l-tiles of 64
#define DD 100
#define FF 50
#define FP 64
#define YY 8000
#define KS 9
#define PADW 4
#define LT 32
#define NLB2 80
#define YB 64
#define ST 67          // sAF row stride in floats

typedef __attribute__((ext_vector_type(8))) short short8;
typedef __attribute__((ext_vector_type(4))) float f32x4;
typedef float f32x4u __attribute__((ext_vector_type(4), aligned(4)));

__device__ inline f32x4 mfma_bf16(short8 a, short8 b, f32x4 c) {
    return __builtin_amdgcn_mfma_f32_16x16x32_bf16(a, b, c, 0, 0, 0);
}

__device__ inline unsigned short f2bf(float x) {
    unsigned int u = __builtin_bit_cast(unsigned int, x);
    unsigned int r = u + 0x7fffu + ((u >> 16) & 1u);
    return (unsigned short)(r >> 16);
}

__device__ inline void gll16(const void* g, void* l) {
    __builtin_amdgcn_global_load_lds(
        (const __attribute__((address_space(1))) void*)g,
        (__attribute__((address_space(3))) void*)l, 16, 0, 0);
}

// byte offset of h[b][l][f] in the tiled-swizzled hS image (8192 B per 64-l tile)
__device__ inline size_t hswz(int b, int l, int f) {
    int tile = l >> 6, row = l & 63;
    return ((size_t)b * NT + tile) * 8192 + row * 128 +
           (((f >> 3) * 16) ^ ((row & 7) << 4)) + (f & 7) * 2;
}
// byte offset of hT[b][f][l] in the tiled-swizzled hTS image (rows = f, cols = l&63)
__device__ inline size_t htswz(int b, int l, int f) {
    int tile = l >> 6, col = l & 63;
    return ((size_t)b * NT + tile) * 8192 + f * 128 +
           (((col >> 3) * 16) ^ ((f & 7) << 4)) + (col & 7) * 2;
}

// ---- prep: conv_w [F][D][K] -> wT [F][K][D]; U_w fp32 -> bf16 [Y][64] ----
__global__ void k_prep(const float* __restrict__ cw, float* __restrict__ wT,
                       const float* __restrict__ Uw, unsigned short* __restrict__ Ub) {
    int i = blockIdx.x * blockDim.x + threadIdx.x;
    if (i < FF * DD * KS) {
        int f = i / (DD * KS);
        int r = i - f * (DD * KS);
        int d = r / KS;
        int k = r - d * KS;
        wT[(f * KS + k) * DD + d] = cw[i];
    }
    if (i < YY * FP) {
        int y = i >> 6, f = i & 63;
        float v = (f < FF) ? Uw[y * FF + f] : 0.f;
        Ub[i] = f2bf(v);
    }
}

// ---- kernel A: embed + conv1d + tanh -> swizzled hS, hTS ----
__global__ __launch_bounds__(256, 4) void k_conv(const int* __restrict__ x,
                                                 const float* __restrict__ embW,
                                                 const float* __restrict__ wT,
                                                 const float* __restrict__ cb,
                                                 char* __restrict__ hS,
                                                 char* __restrict__ hTS) {
    __shared__ float sE[(LT + 8) * DD];
    __shared__ int sX[LT + 8];
    int b = blockIdx.x / NLB2;
    int l0 = (blockIdx.x % NLB2) * LT;
    int tid = threadIdx.x;

    if (tid < LT + 8) {
        int gl = l0 - PADW + tid;
        sX[tid] = (gl >= 0 && gl < LL) ? x[b * LL + gl] : -1;
    }
    __syncthreads();
    for (int i = tid; i < (LT + 8) * (DD / 4); i += 256) {
        int row = i / (DD / 4);
        int d4 = i - row * (DD / 4);
        int id = sX[row];
        float4 v = make_float4(0.f, 0.f, 0.f, 0.f);
        if (id >= 0) v = *(const float4*)(embW + (size_t)id * DD + d4 * 4);
        *(float4*)&sE[row * DD + d4 * 4] = v;
    }
    __syncthreads();

    int f0 = tid & 31;
    int f1 = f0 + 32;
    bool f1a = (f1 < FF);
    int lb = tid >> 5;
    const float* eRow = &sE[lb * 4 * DD];
    const float* w0p = wT + (size_t)f0 * (KS * DD);
    const float* w1p = wT + (size_t)(f1a ? f1 : f0) * (KS * DD);
    float acc0[4] = {0.f, 0.f, 0.f, 0.f};
    float acc1[4] = {0.f, 0.f, 0.f, 0.f};

    for (int d4 = 0; d4 < DD / 4; ++d4) {
        float4 e[12];
#pragma unroll
        for (int r = 0; r < 12; ++r)
            e[r] = *(const float4*)(eRow + r * DD + d4 * 4);
#pragma unroll
        for (int k = 0; k < KS; ++k) {
            float4 wa = *(const float4*)(w0p + k * DD + d4 * 4);
            float4 wb = *(const float4*)(w1p + k * DD + d4 * 4);
#pragma unroll
            for (int j = 0; j < 4; ++j) {
                float4 ev = e[k + j];
                acc0[j] += wa.x * ev.x + wa.y * ev.y + wa.z * ev.z + wa.w * ev.w;
                acc1[j] += wb.x * ev.x + wb.y * ev.y + wb.z * ev.z + wb.w * ev.w;
            }
        }
    }
    float b0 = cb[f0];
    float b1 = f1a ? cb[f1] : 0.f;
    float t0[4], t1[4];
#pragma unroll
    for (int j = 0; j < 4; ++j) {
        int l = l0 + lb * 4 + j;
        bool lv = (l < LL);
        t0[j] = lv ? tanhf(acc0[j] + b0) : 0.f;
        t1[j] = (lv && f1a) ? tanhf(acc1[j] + b1) : 0.f;
        *(unsigned short*)(hS + hswz(b, l, f0)) = f2bf(t0[j]);
        *(unsigned short*)(hS + hswz(b, l, f1)) = f2bf(t1[j]);
    }
    int lc = l0 + lb * 4;
    unsigned long long p0 = (unsigned long long)f2bf(t0[0]) | ((unsigned long long)f2bf(t0[1]) << 16)
                          | ((unsigned long long)f2bf(t0[2]) << 32) | ((unsigned long long)f2bf(t0[3]) << 48);
    unsigned long long p1 = (unsigned long long)f2bf(t1[0]) | ((unsigned long long)f2bf(t1[1]) << 16)
                          | ((unsigned long long)f2bf(t1[2]) << 32) | ((unsigned long long)f2bf(t1[3]) << 48);
    *(unsigned long long*)(hTS + htswz(b, lc, f0)) = p0;
    *(unsigned long long*)(hTS + htswz(b, lc, f1)) = p1;
}

// ---- kernel B: fused scores(MFMA) -> softmax -> alpha -> m(MFMA) -> yhat -> BCE ----
__global__ __launch_bounds__(256, 4) void k_attn2(const char* __restrict__ hS,
                                                  const char* __restrict__ hTS,
                                                  const unsigned short* __restrict__ Ub,
                                                  const float* __restrict__ fw,
                                                  const float* __restrict__ fb,
                                                  const float* __restrict__ tgt,
                                                  float* __restrict__ out,
                                                  float* __restrict__ lossAcc) {
    __shared__ char sH[8192];        // [64 l][64 f] bf16, XOR-swizzled (DMA-staged)
    __shared__ char sHT[8192];       // [64 f][64 l] bf16, XOR-swizzled (DMA-staged)
    __shared__ float sAF[64 * ST];   // alpha fp32 [64 y][64 l], stride 67
    __shared__ float sRed[256];
    __shared__ float sInv[64];

    int b = blockIdx.x & 7;
    int y0 = (blockIdx.x >> 3) * YB;
    int tid = threadIdx.x;
    int w = tid >> 6;
    int lane = tid & 63;
    int lm = lane & 15, g = lane >> 4;

    const char* hSb = hS + (size_t)b * NT * 8192;
    const char* hTSb = hTS + (size_t)b * NT * 8192;

    short8 uf[4][2];
#pragma unroll
    for (int yt = 0; yt < 4; ++yt)
#pragma unroll
        for (int kh = 0; kh < 2; ++kh)
            uf[yt][kh] = *(const short8*)(Ub + (size_t)(y0 + yt * 16 + lm) * FP + g * 8 + kh * 32);

    int r = w * 16 + lm;
    int rx = (r & 7) << 4;
    int ub = w * 2048;
    int gofs = ub + lane * 16;

    // ---------------- pass 1: softmax denominators ----------------
    float ssum[4] = {0.f, 0.f, 0.f, 0.f};
    for (int lt = 0; lt < NT; ++lt) {
        const char* src = hSb + lt * 8192;
        gll16(src + gofs, sH + ub);
        gll16(src + gofs + 1024, sH + ub + 1024);
        __syncthreads();
        short8 a0 = *(const short8*)&sH[r * 128 + ((g * 16) ^ rx)];
        short8 a1 = *(const short8*)&sH[r * 128 + ((g * 16 + 64) ^ rx)];
        int lbase = lt * 64 + w * 16 + g * 4;
#pragma unroll
        for (int yt = 0; yt < 4; ++yt) {
            f32x4 c = {0.f, 0.f, 0.f, 0.f};
            c = mfma_bf16(a0, uf[yt][0], c);
            c = mfma_bf16(a1, uf[yt][1], c);
            float p = 0.f;
#pragma unroll
            for (int j = 0; j < 4; ++j)
                p += (lbase + j < LL) ? __expf(c[j]) : 0.f;
            ssum[yt] += p;
        }
        __syncthreads();
    }
#pragma unroll
    for (int yt = 0; yt < 4; ++yt) {
        float s = ssum[yt];
        s += __shfl_xor(s, 16);
        s += __shfl_xor(s, 32);
        if (g == 0) sRed[w * 64 + yt * 16 + lm] = s;
    }
    __syncthreads();
    if (tid < 64) {
        float s = sRed[tid] + sRed[64 + tid] + sRed[128 + tid] + sRed[192 + tid];
        sInv[tid] = 1.f / s;
    }
    __syncthreads();

    // ---------------- pass 2: alpha out + m accumulation ----------------
    f32x4 macc[4];
#pragma unroll
    for (int ft = 0; ft < 4; ++ft) macc[ft] = (f32x4){0.f, 0.f, 0.f, 0.f};

    float* alphaBase = out + 64001;
    for (int lt = 0; lt < NT; ++lt) {
        const char* srcH = hSb + lt * 8192;
        const char* srcT = hTSb + lt * 8192;
        gll16(srcH + gofs, sH + ub);
        gll16(srcH + gofs + 1024, sH + ub + 1024);
        gll16(srcT + gofs, sHT + ub);
        gll16(srcT + gofs + 1024, sHT + ub + 1024);
        __syncthreads();                       // bar1: tiles staged

        short8 a0 = *(const short8*)&sH[r * 128 + ((g * 16) ^ rx)];
        short8 a1 = *(const short8*)&sH[r * 128 + ((g * 16 + 64) ^ rx)];
        int lbase = lt * 64 + w * 16 + g * 4;
#pragma unroll
        for (int yt = 0; yt < 4; ++yt) {
            f32x4 c = {0.f, 0.f, 0.f, 0.f};
            c = mfma_bf16(a0, uf[yt][0], c);
            c = mfma_bf16(a1, uf[yt][1], c);
            float inv = sInv[yt * 16 + lm];
            float a[4];
#pragma unroll
            for (int j = 0; j < 4; ++j)
                a[j] = (lbase + j < LL) ? __expf(c[j]) * inv : 0.f;
            int yl = yt * 16 + lm;
            *(f32x4*)&sAF[yl * ST + w * 16 + g * 4] = (f32x4){a[0], a[1], a[2], a[3]};
        }
        __syncthreads();                       // bar2: sAF ready

        // pa fragments derived from sAF (bf16 pack in-reg)
        int yr = w * 16 + lm;
        short8 pa0, pa1;
#pragma unroll
        for (int e = 0; e < 8; ++e) {
            pa0[e] = (short)f2bf(sAF[yr * ST + g * 8 + e]);
            pa1[e] = (short)f2bf(sAF[yr * ST + 32 + g * 8 + e]);
        }
#pragma unroll
        for (int ft = 0; ft < 4; ++ft) {
            int fr = ft * 16 + lm;
            int fx = (fr & 7) << 4;
            short8 b0 = *(const short8*)&sHT[fr * 128 + ((g * 16) ^ fx)];
            short8 b1 = *(const short8*)&sHT[fr * 128 + ((g * 16 + 64) ^ fx)];
            macc[ft] = mfma_bf16(pa0, b0, macc[ft]);
            macc[ft] = mfma_bf16(pa1, b1, macc[ft]);
        }
        // coalesced alpha dump (2500 % 4 == 0 -> full float4s only)
        int l0t = lt * 64;
#pragma unroll
        for (int it = 0; it < 4; ++it) {
            int i = tid + it * 256;
            int row = i >> 4;
            int c4 = (i & 15) * 4;
            int l = l0t + c4;
            if (l < LL) {
                f32x4 v = *(f32x4*)&sAF[row * ST + c4];
                __builtin_nontemporal_store(v,
                    (f32x4u*)(alphaBase + (size_t)(b * YY + y0 + row) * LL + l));
            }
        }
        __syncthreads();                       // bar3: reads done before next DMA
    }

    // ---------------- epilogue: yhat + BCE ----------------
    float bsum = 0.f;
#pragma unroll
    for (int j = 0; j < 4; ++j) {
        int y = y0 + w * 16 + g * 4 + j;
        float z = 0.f;
#pragma unroll
        for (int ft = 0; ft < 4; ++ft) {
            int f = ft * 16 + lm;
            float fwv = (f < FF) ? fw[(size_t)y * FF + f] : 0.f;
            z += macc[ft][j] * fwv;
        }
        z += __shfl_xor(z, 1);
        z += __shfl_xor(z, 2);
        z += __shfl_xor(z, 4);
        z += __shfl_xor(z, 8);
        if (lm == 0) {
            z += fb[y];
            out[b * YY + y] = z;
            float t = tgt[b * YY + y];
            bsum += fmaxf(z, 0.f) - z * t + log1pf(__expf(-fabsf(z)));
        }
    }
    bsum += __shfl_xor(bsum, 16);
    bsum += __shfl_xor(bsum, 32);
    if (lane == 0) atomicAdd(lossAcc, bsum);
}

// ---- kernel C: finalize loss ----
__global__ void k_loss(const float* __restrict__ acc, float* __restrict__ out) {
    out[64000] = acc[0] / (float)(BB * YY);
}

extern "C" void kernel_launch(void* const* d_in, const int* in_sizes, int n_in,
                              void* d_out, int out_size, void* d_ws, size_t ws_size,
                              hipStream_t stream) {
    const int*   x    = (const int*)d_in[0];
    const float* tgt  = (const float*)d_in[1];
    const float* embW = (const float*)d_in[2];
    const float* cw   = (const float*)d_in[3];
    const float* cb   = (const float*)d_in[4];
    const float* Uw   = (const float*)d_in[5];
    const float* fw   = (const float*)d_in[6];
    const float* fb   = (const float*)d_in[7];
    float* out = (float*)d_out;

    float*          lossAcc = (float*)d_ws;
    float*          wT  = (float*)((char*)d_ws + 256);
    unsigned short* Ub  = (unsigned short*)((char*)d_ws + 184320);
    char*           hS  = (char*)d_ws + 1212416;   // 8 * 40 * 8192 = 2.62 MB
    char*           hTS = (char*)d_ws + 3833856;   // 8 * 40 * 8192 = 2.62 MB

    hipMemsetAsync(d_ws, 0, 4, stream);
    k_prep<<<(YY * FP + 255) / 256, 256, 0, stream>>>(cw, wT, Uw, Ub);
    k_conv<<<BB * NLB2, 256, 0, stream>>>(x, embW, wT, cb, hS, hTS);
    k_attn2<<<125 * 8, 256, 0, stream>>>(hS, hTS, Ub, fw, fb, tgt, out, lossAcc);
    k_loss<<<1, 1, 0, stream>>>(lossAcc, out);
}

// Round 5
// 458.189 us; speedup vs baseline: 8.6899x; 1.0705x over previous
//
#include <hip/hip_runtime.h>
#include <hip/hip_bf16.h>
#include <math.h>

#define BB 8
#define LL 2500
#define LPAD 2560
#define DD 100
#define FF 50
#define FP 64
#define YY 8000
#define KS 9
#define PADW 4
#define LT 32
#define NLB2 80
#define YB 64
#define STF 132    // sAF row stride (floats)
#define STB 136    // sAB row stride (shorts)

typedef __attribute__((ext_vector_type(8))) short short8;
typedef __attribute__((ext_vector_type(4))) float f32x4;
typedef float f32x4u __attribute__((ext_vector_type(4), aligned(4)));

__device__ inline f32x4 mfma_bf16(short8 a, short8 b, f32x4 c) {
    return __builtin_amdgcn_mfma_f32_16x16x32_bf16(a, b, c, 0, 0, 0);
}

__device__ inline unsigned short f2bf(float x) {
    unsigned int u = __builtin_bit_cast(unsigned int, x);
    unsigned int r = u + 0x7fffu + ((u >> 16) & 1u);
    return (unsigned short)(r >> 16);
}

__device__ inline unsigned long long pack4bf(const float* a) {
    return (unsigned long long)f2bf(a[0])
         | ((unsigned long long)f2bf(a[1]) << 16)
         | ((unsigned long long)f2bf(a[2]) << 32)
         | ((unsigned long long)f2bf(a[3]) << 48);
}

// ---- prep: conv_w [F][D][K] -> wT [F][K][D]; U_w fp32 -> bf16 [Y][64] ----
__global__ void k_prep(const float* __restrict__ cw, float* __restrict__ wT,
                       const float* __restrict__ Uw, unsigned short* __restrict__ Ub) {
    int i = blockIdx.x * blockDim.x + threadIdx.x;
    if (i < FF * DD * KS) {
        int f = i / (DD * KS);
        int r = i - f * (DD * KS);
        int d = r / KS;
        int k = r - d * KS;
        wT[(f * KS + k) * DD + d] = cw[i];
    }
    if (i < YY * FP) {
        int y = i >> 6, f = i & 63;
        float v = (f < FF) ? Uw[y * FF + f] : 0.f;
        Ub[i] = f2bf(v);
    }
}

// ---- kernel A: embed + conv1d + tanh -> hB[b][2560][64], hT[b][64][2560] (plain bf16) ----
__global__ __launch_bounds__(256, 4) void k_conv(const int* __restrict__ x,
                                                 const float* __restrict__ embW,
                                                 const float* __restrict__ wT,
                                                 const float* __restrict__ cb,
                                                 unsigned short* __restrict__ hB,
                                                 unsigned short* __restrict__ hT) {
    __shared__ float sE[(LT + 8) * DD];
    __shared__ int sX[LT + 8];
    int b = blockIdx.x / NLB2;
    int l0 = (blockIdx.x % NLB2) * LT;
    int tid = threadIdx.x;

    if (tid < LT + 8) {
        int gl = l0 - PADW + tid;
        sX[tid] = (gl >= 0 && gl < LL) ? x[b * LL + gl] : -1;
    }
    __syncthreads();
    for (int i = tid; i < (LT + 8) * (DD / 4); i += 256) {
        int row = i / (DD / 4);
        int d4 = i - row * (DD / 4);
        int id = sX[row];
        float4 v = make_float4(0.f, 0.f, 0.f, 0.f);
        if (id >= 0) v = *(const float4*)(embW + (size_t)id * DD + d4 * 4);
        *(float4*)&sE[row * DD + d4 * 4] = v;
    }
    __syncthreads();

    int f0 = tid & 31;
    int f1 = f0 + 32;
    bool f1a = (f1 < FF);
    int lb = tid >> 5;
    const float* eRow = &sE[lb * 4 * DD];
    const float* w0p = wT + (size_t)f0 * (KS * DD);
    const float* w1p = wT + (size_t)(f1a ? f1 : f0) * (KS * DD);
    float acc0[4] = {0.f, 0.f, 0.f, 0.f};
    float acc1[4] = {0.f, 0.f, 0.f, 0.f};

    for (int d4 = 0; d4 < DD / 4; ++d4) {
        float4 e[12];
#pragma unroll
        for (int r = 0; r < 12; ++r)
            e[r] = *(const float4*)(eRow + r * DD + d4 * 4);
#pragma unroll
        for (int k = 0; k < KS; ++k) {
            float4 wa = *(const float4*)(w0p + k * DD + d4 * 4);
            float4 wb = *(const float4*)(w1p + k * DD + d4 * 4);
#pragma unroll
            for (int j = 0; j < 4; ++j) {
                float4 ev = e[k + j];
                acc0[j] += wa.x * ev.x + wa.y * ev.y + wa.z * ev.z + wa.w * ev.w;
                acc1[j] += wb.x * ev.x + wb.y * ev.y + wb.z * ev.z + wb.w * ev.w;
            }
        }
    }
    float b0 = cb[f0];
    float b1 = f1a ? cb[f1] : 0.f;
    float t0[4], t1[4];
#pragma unroll
    for (int j = 0; j < 4; ++j) {
        int l = l0 + lb * 4 + j;
        bool lv = (l < LL);
        t0[j] = lv ? tanhf(acc0[j] + b0) : 0.f;
        t1[j] = (lv && f1a) ? tanhf(acc1[j] + b1) : 0.f;
        size_t base = ((size_t)b * LPAD + l) * FP;
        hB[base + f0] = f2bf(t0[j]);
        hB[base + f1] = f2bf(t1[j]);
    }
    int lc = l0 + lb * 4;
    *(unsigned long long*)&hT[((size_t)b * FP + f0) * LPAD + lc] = pack4bf(t0);
    *(unsigned long long*)&hT[((size_t)b * FP + f1) * LPAD + lc] = pack4bf(t1);
}

// ---- kernel B: fused scores(MFMA, L2-direct) -> softmax -> alpha -> m(MFMA) -> yhat/BCE ----
__global__ __launch_bounds__(256) void k_attn3(const unsigned short* __restrict__ hB,
                                               const unsigned short* __restrict__ hT,
                                               const unsigned short* __restrict__ Ub,
                                               const float* __restrict__ fw,
                                               const float* __restrict__ fb,
                                               const float* __restrict__ tgt,
                                               float* __restrict__ out,
                                               float* __restrict__ lossAcc) {
    __shared__ float sAF[64 * STF];          // alpha fp32 [64 y][128 l]
    __shared__ unsigned short sAB[64 * STB]; // alpha bf16 [64 y][128 l]
    __shared__ float sRed[256];
    __shared__ float sInv[64];

    int b = blockIdx.x & 7;                  // b -> XCD pin for L2 locality
    int y0 = (blockIdx.x >> 3) * YB;
    int tid = threadIdx.x;
    int w = tid >> 6;
    int lane = tid & 63;
    int lm = lane & 15, g = lane >> 4;

    const unsigned short* hBb = hB + (size_t)b * LPAD * FP;
    const unsigned short* hTb = hT + (size_t)b * FP * LPAD;

    short8 uf[4][2];
#pragma unroll
    for (int yt = 0; yt < 4; ++yt)
#pragma unroll
        for (int kh = 0; kh < 2; ++kh)
            uf[yt][kh] = *(const short8*)(Ub + (size_t)(y0 + yt * 16 + lm) * FP + kh * 32 + g * 8);

    // ---------------- pass 1: softmax denominators (barrier-free) ----------------
    float ssum[4] = {0.f, 0.f, 0.f, 0.f};
    for (int t = 0; t < 20; ++t) {
        int lw = t * 128 + w * 32;
        const unsigned short* base = hBb + (size_t)lw * FP;
        short8 a00 = *(const short8*)(base + lm * FP + g * 8);
        short8 a01 = *(const short8*)(base + lm * FP + 32 + g * 8);
        short8 a10 = *(const short8*)(base + (16 + lm) * FP + g * 8);
        short8 a11 = *(const short8*)(base + (16 + lm) * FP + 32 + g * 8);
        int l0a = lw + g * 4, l0b = lw + 16 + g * 4;
#pragma unroll
        for (int yt = 0; yt < 4; ++yt) {
            f32x4 c0 = {0.f, 0.f, 0.f, 0.f};
            c0 = mfma_bf16(a00, uf[yt][0], c0);
            c0 = mfma_bf16(a01, uf[yt][1], c0);
            f32x4 c1 = {0.f, 0.f, 0.f, 0.f};
            c1 = mfma_bf16(a10, uf[yt][0], c1);
            c1 = mfma_bf16(a11, uf[yt][1], c1);
            float p = 0.f;
#pragma unroll
            for (int j = 0; j < 4; ++j) {
                p += (l0a + j < LL) ? __expf(c0[j]) : 0.f;
                p += (l0b + j < LL) ? __expf(c1[j]) : 0.f;
            }
            ssum[yt] += p;
        }
    }
#pragma unroll
    for (int yt = 0; yt < 4; ++yt) {
        float s = ssum[yt];
        s += __shfl_xor(s, 16);
        s += __shfl_xor(s, 32);
        if (g == 0) sRed[w * 64 + yt * 16 + lm] = s;
    }
    __syncthreads();
    if (tid < 64)
        sInv[tid] = 1.f / (sRed[tid] + sRed[64 + tid] + sRed[128 + tid] + sRed[192 + tid]);
    __syncthreads();

    // ---------------- pass 2: alpha + m over 128-l super-tiles ----------------
    f32x4 macc[4];
#pragma unroll
    for (int yt = 0; yt < 4; ++yt) macc[yt] = (f32x4){0.f, 0.f, 0.f, 0.f};

    float* alphaBase = out + 64001;
    for (int t = 0; t < 20; ++t) {
        int lw = t * 128 + w * 32;
        const unsigned short* base = hBb + (size_t)lw * FP;
        short8 a00 = *(const short8*)(base + lm * FP + g * 8);
        short8 a01 = *(const short8*)(base + lm * FP + 32 + g * 8);
        short8 a10 = *(const short8*)(base + (16 + lm) * FP + g * 8);
        short8 a11 = *(const short8*)(base + (16 + lm) * FP + 32 + g * 8);
        int l0a = lw + g * 4, l0b = lw + 16 + g * 4;
#pragma unroll
        for (int yt = 0; yt < 4; ++yt) {
            f32x4 c0 = {0.f, 0.f, 0.f, 0.f};
            c0 = mfma_bf16(a00, uf[yt][0], c0);
            c0 = mfma_bf16(a01, uf[yt][1], c0);
            f32x4 c1 = {0.f, 0.f, 0.f, 0.f};
            c1 = mfma_bf16(a10, uf[yt][0], c1);
            c1 = mfma_bf16(a11, uf[yt][1], c1);
            float inv = sInv[yt * 16 + lm];
            float a0v[4], a1v[4];
#pragma unroll
            for (int j = 0; j < 4; ++j) {
                a0v[j] = (l0a + j < LL) ? __expf(c0[j]) * inv : 0.f;
                a1v[j] = (l0b + j < LL) ? __expf(c1[j]) * inv : 0.f;
            }
            int yl = yt * 16 + lm;
            *(f32x4*)&sAF[yl * STF + w * 32 + g * 4] = (f32x4){a0v[0], a0v[1], a0v[2], a0v[3]};
            *(f32x4*)&sAF[yl * STF + w * 32 + 16 + g * 4] = (f32x4){a1v[0], a1v[1], a1v[2], a1v[3]};
            *(unsigned long long*)&sAB[yl * STB + w * 32 + g * 4] = pack4bf(a0v);
            *(unsigned long long*)&sAB[yl * STB + w * 32 + 16 + g * 4] = pack4bf(a1v);
        }
        __syncthreads();
        // m MFMA: wave w owns f-rows w*16..w*16+15, loops all 4 k-chunks
#pragma unroll
        for (int ks = 0; ks < 4; ++ks) {
            int k0 = ks * 32;
            short8 bf = *(const short8*)(hTb + (size_t)(w * 16 + lm) * LPAD + t * 128 + k0 + g * 8);
#pragma unroll
            for (int yt = 0; yt < 4; ++yt) {
                short8 pa = *(const short8*)&sAB[(yt * 16 + lm) * STB + k0 + g * 8];
                macc[yt] = mfma_bf16(pa, bf, macc[yt]);
            }
        }
        // alpha dump: 512 B contiguous per y-row
#pragma unroll
        for (int it = 0; it < 8; ++it) {
            int i = tid + it * 256;
            int row = i >> 5;
            int c4 = (i & 31) * 4;
            int l = t * 128 + c4;
            if (l < LL) {
                f32x4 v = *(f32x4*)&sAF[row * STF + c4];
                __builtin_nontemporal_store(v,
                    (f32x4u*)(alphaBase + (size_t)(b * YY + y0 + row) * LL + l));
            }
        }
        __syncthreads();
    }

    // ---------------- epilogue: yhat + BCE ----------------
#pragma unroll
    for (int yt = 0; yt < 4; ++yt) {
        float z = 0.f;
#pragma unroll
        for (int j = 0; j < 4; ++j) {
            int y = y0 + yt * 16 + g * 4 + j;
            int f = w * 16 + lm;
            float fwv = (f < FF) ? fw[(size_t)y * FF + f] : 0.f;
            float p = macc[yt][j] * fwv;
            p += __shfl_xor(p, 1);
            p += __shfl_xor(p, 2);
            p += __shfl_xor(p, 4);
            p += __shfl_xor(p, 8);
            if (lm == 0) sRed[w * 64 + yt * 16 + g * 4 + j] = p;
        }
    }
    __syncthreads();
    if (tid < 64) {
        int y = y0 + tid;
        float z = sRed[tid] + sRed[64 + tid] + sRed[128 + tid] + sRed[192 + tid] + fb[y];
        out[b * YY + y] = z;
        float tg = tgt[b * YY + y];
        float bce = fmaxf(z, 0.f) - z * tg + log1pf(__expf(-fabsf(z)));
        bce += __shfl_xor(bce, 1);
        bce += __shfl_xor(bce, 2);
        bce += __shfl_xor(bce, 4);
        bce += __shfl_xor(bce, 8);
        bce += __shfl_xor(bce, 16);
        bce += __shfl_xor(bce, 32);
        if (tid == 0) atomicAdd(lossAcc, bce);
    }
}

// ---- kernel C: finalize loss ----
__global__ void k_loss(const float* __restrict__ acc, float* __restrict__ out) {
    out[64000] = acc[0] / (float)(BB * YY);
}

extern "C" void kernel_launch(void* const* d_in, const int* in_sizes, int n_in,
                              void* d_out, int out_size, void* d_ws, size_t ws_size,
                              hipStream_t stream) {
    const int*   x    = (const int*)d_in[0];
    const float* tgt  = (const float*)d_in[1];
    const float* embW = (const float*)d_in[2];
    const float* cw   = (const float*)d_in[3];
    const float* cb   = (const float*)d_in[4];
    const float* Uw   = (const float*)d_in[5];
    const float* fw   = (const float*)d_in[6];
    const float* fb   = (const float*)d_in[7];
    float* out = (float*)d_out;

    float*          lossAcc = (float*)d_ws;
    float*          wT = (float*)((char*)d_ws + 256);
    unsigned short* Ub = (unsigned short*)((char*)d_ws + 184320);
    unsigned short* hB = (unsigned short*)((char*)d_ws + 1212416);  // 8*2560*64*2 B
    unsigned short* hT = (unsigned short*)((char*)d_ws + 3833856);  // 8*64*2560*2 B

    hipMemsetAsync(d_ws, 0, 4, stream);
    k_prep<<<(YY * FP + 255) / 256, 256, 0, stream>>>(cw, wT, Uw, Ub);
    k_conv<<<BB * NLB2, 256, 0, stream>>>(x, embW, wT, cb, hB, hT);
    k_attn3<<<125 * 8, 256, 0, stream>>>(hB, hT, Ub, fw, fb, tgt, out, lossAcc);
    k_loss<<<1, 1, 0, stream>>>(lossAcc, out);
}